// Round 1
// baseline (2774.295 us; speedup 1.0000x reference)
//
#include <hip/hip_runtime.h>
#include <hip/hip_bf16.h>

#define E_ 8
#define D_ 1024
#define F_ 4096
#define K_ 2
#define BM 64
#define BF 128

typedef __attribute__((ext_vector_type(8))) short short8;
typedef __attribute__((ext_vector_type(4))) float f32x4;

__device__ __forceinline__ unsigned short f2bf(float f){
  union { __hip_bfloat16 h; unsigned short u; } c;
  c.h = __float2bfloat16(f);
  return c.u;
}

__device__ __forceinline__ short8 cvt8(float4 a, float4 b){
  short8 r;
  r[0]=(short)f2bf(a.x); r[1]=(short)f2bf(a.y); r[2]=(short)f2bf(a.z); r[3]=(short)f2bf(a.w);
  r[4]=(short)f2bf(b.x); r[5]=(short)f2bf(b.y); r[6]=(short)f2bf(b.z); r[7]=(short)f2bf(b.w);
  return r;
}

template<bool B16>
__device__ __forceinline__ short8 loadw8(const void* __restrict__ base, size_t off){
  if constexpr (B16) {
    return *reinterpret_cast<const short8*>(reinterpret_cast<const __hip_bfloat16*>(base) + off);
  } else {
    const float4* p = reinterpret_cast<const float4*>(reinterpret_cast<const float*>(base) + off);
    float4 a = p[0]; float4 b = p[1];
    return cvt8(a, b);
  }
}

__device__ __forceinline__ float gelu_f(float v){
  const float c0 = 0.7978845608028654f;   // sqrt(2/pi)
  float z = c0 * (v + 0.044715f * v * v * v);
  float e = __expf(2.0f * z);
  float t = 1.0f - 2.0f / (1.0f + e);     // tanh(z), stable for |z| large
  return 0.5f * v * (1.0f + t);
}

// ---------------- gating ----------------
__global__ void gate_kernel(const float* __restrict__ x, const float* __restrict__ gw,
                            int* __restrict__ tidx, float* __restrict__ tw,
                            int* __restrict__ counts, int T){
  int wid = threadIdx.x >> 6, lane = threadIdx.x & 63;
  int t = blockIdx.x * 4 + wid;
  if (t >= T) return;
  const float* xr = x + (size_t)t * D_;
  double acc[E_];
  #pragma unroll
  for (int e = 0; e < E_; ++e) acc[e] = 0.0;
  #pragma unroll
  for (int j = 0; j < 16; ++j){
    float xv = xr[j*64 + lane];
    #pragma unroll
    for (int e = 0; e < E_; ++e)
      acc[e] += (double)xv * (double)gw[e*D_ + j*64 + lane];
  }
  #pragma unroll
  for (int e = 0; e < E_; ++e){
    #pragma unroll
    for (int off = 32; off >= 1; off >>= 1)
      acc[e] += __shfl_xor(acc[e], off);
  }
  if (lane == 0){
    float l[E_];
    #pragma unroll
    for (int e = 0; e < E_; ++e) l[e] = (float)acc[e];
    int i0 = 0; float v0 = l[0];
    #pragma unroll
    for (int e = 1; e < E_; ++e) if (l[e] > v0){ v0 = l[e]; i0 = e; }
    int i1 = -1; float v1 = -1e30f;
    #pragma unroll
    for (int e = 0; e < E_; ++e) if (e != i0 && l[e] > v1){ v1 = l[e]; i1 = e; }
    float e1 = expf(v1 - v0);
    float s = 1.0f + e1;
    tidx[2*t] = i0; tidx[2*t+1] = i1;
    tw[2*t] = 1.0f / s; tw[2*t+1] = e1 / s;
    atomicAdd(&counts[i0], 1);
    atomicAdd(&counts[i1], 1);
  }
}

__global__ void init_kernel(int* rowTok, float* rowW, int* counts, int* cursors, int nSlots){
  int i = blockIdx.x * blockDim.x + threadIdx.x;
  if (i < nSlots){ rowTok[i] = 0; rowW[i] = 0.0f; }
  if (i < E_){ counts[i] = 0; cursors[i] = 0; }
}

__global__ void scan_kernel(const int* counts, int* aligned){
  if (threadIdx.x == 0 && blockIdx.x == 0){
    int s = 0;
    for (int e = 0; e < E_; ++e){ aligned[e] = s; s += ((counts[e] + BM - 1) / BM) * BM; }
    aligned[E_] = s;
  }
}

__global__ void scatter_kernel(const int* __restrict__ tidx, const float* __restrict__ tw,
                               const int* __restrict__ aligned, int* cursors,
                               int* __restrict__ rowTok, float* __restrict__ rowW, int T){
  int t = blockIdx.x * blockDim.x + threadIdx.x;
  if (t >= T) return;
  for (int k = 0; k < K_; ++k){
    int e = tidx[2*t + k];
    int pos = aligned[e] + atomicAdd(&cursors[e], 1);
    rowTok[pos] = t;
    rowW[pos] = tw[2*t + k];
  }
}

// ---------------- weight fp32 -> bf16 ----------------
__global__ void cvtw_kernel(const float* __restrict__ src, __hip_bfloat16* __restrict__ dst, int n4){
  int stride = gridDim.x * blockDim.x;
  for (int i = blockIdx.x * blockDim.x + threadIdx.x; i < n4; i += stride){
    float4 v = reinterpret_cast<const float4*>(src)[i];
    uint2 p;
    p.x = (unsigned)f2bf(v.x) | ((unsigned)f2bf(v.y) << 16);
    p.y = (unsigned)f2bf(v.z) | ((unsigned)f2bf(v.w) << 16);
    reinterpret_cast<uint2*>(dst)[i] = p;
  }
}

// ---------------- fused expert-MLP tile kernel ----------------
// LDS layout (dynamic):
#define X_OFF 0
#define H_OFF (64*2048)                    // 131072: x tile 64 x 1024 bf16, XOR-swizzled
#define H_STRIDE 272                       // 128 bf16 + 8 pad
#define TOK_OFF (H_OFF + 64*H_STRIDE)      // 148480
#define WV_OFF (TOK_OFF + 256)
#define SMEM_BYTES (WV_OFF + 256)          // 148992

template<bool B16>
__global__ __launch_bounds__(512) void moe_tile_kernel(
    const float* __restrict__ x,
    const void* __restrict__ wfc,   // [E][F][D] bf16 (ws) or fp32 (input)
    const void* __restrict__ wpj,   // [E][D][F]
    const float* __restrict__ bfc,  // [E][F]
    const float* __restrict__ bpj,  // [E][D]
    const int* __restrict__ rowTok, const float* __restrict__ rowW,
    const int* __restrict__ aligned, float* __restrict__ out)
{
  extern __shared__ char smem[];
  int tb = blockIdx.x * BM;
  if (tb >= aligned[E_]) return;
  int e = 0;
  #pragma unroll
  for (int i = 1; i < E_; ++i) if (tb >= aligned[i]) e = i;

  const int tid = threadIdx.x;
  const int wid = tid >> 6, lane = tid & 63;
  const int lr = lane & 15, lg = lane >> 4;

  int* s_tok = (int*)(smem + TOK_OFF);
  float* s_w = (float*)(smem + WV_OFF);
  if (tid < BM){ s_tok[tid] = rowTok[tb + tid]; s_w[tid] = rowW[tb + tid]; }
  __syncthreads();

  // stage x tile (fp32 -> bf16) into swizzled LDS; one wave per row group
  for (int r = wid; r < BM; r += 8){
    const float4* src = reinterpret_cast<const float4*>(x + (size_t)s_tok[r] * D_);
    int sw = (r & 7) << 4;
    #pragma unroll
    for (int i = 0; i < 4; ++i){
      float4 v = src[i*64 + lane];
      uint2 p;
      p.x = (unsigned)f2bf(v.x) | ((unsigned)f2bf(v.y) << 16);
      p.y = (unsigned)f2bf(v.z) | ((unsigned)f2bf(v.w) << 16);
      int byte = r*2048 + (i*64 + lane)*8;
      *reinterpret_cast<uint2*>(smem + (byte ^ sw)) = p;
    }
  }
  __syncthreads();

  const size_t eFD = (size_t)e * F_ * D_;
  const int fcol = wid*16 + lr;    // phase-1 f column (within chunk)
  const int ocol = wid*128 + lr;   // phase-2 base output column

  f32x4 yacc[4][8];
  #pragma unroll
  for (int m = 0; m < 4; ++m)
    #pragma unroll
    for (int n = 0; n < 8; ++n)
      yacc[m][n] = (f32x4){0.f, 0.f, 0.f, 0.f};

  for (int fc = 0; fc < F_/BF; ++fc){
    int f0 = fc * BF;

    // ---- phase 1: h = x @ wfc^T over K=1024 ----
    f32x4 hacc[4];
    #pragma unroll
    for (int m = 0; m < 4; ++m) hacc[m] = (f32x4){0.f, 0.f, 0.f, 0.f};
    size_t wfc_off = eFD + (size_t)(f0 + fcol) * D_ + lg*8;
    for (int ks = 0; ks < 32; ++ks){
      short8 bfrag = loadw8<B16>(wfc, wfc_off + ks*32);
      #pragma unroll
      for (int m = 0; m < 4; ++m){
        int row = m*16 + lr;
        int byte = (row*2048 + (ks*32 + lg*8)*2) ^ ((row & 7) << 4);
        short8 afrag = *reinterpret_cast<const short8*>(smem + byte);
        hacc[m] = __builtin_amdgcn_mfma_f32_16x16x32_bf16(afrag, bfrag, hacc[m], 0, 0, 0);
      }
    }

    // ---- gelu + stage h chunk to LDS ----
    float bias = bfc[e*F_ + f0 + fcol];
    __syncthreads();   // prior phase-2 readers done before overwrite
    #pragma unroll
    for (int m = 0; m < 4; ++m){
      #pragma unroll
      for (int i = 0; i < 4; ++i){
        float g = gelu_f(hacc[m][i] + bias);
        int hrow = m*16 + lg*4 + i;
        *reinterpret_cast<unsigned short*>(smem + H_OFF + hrow*H_STRIDE + fcol*2) = f2bf(g);
      }
    }
    __syncthreads();

    // ---- phase 2: y += h @ wproj_chunk^T (K = BF) ----
    #pragma unroll
    for (int ks = 0; ks < 4; ++ks){
      short8 bfr[8];
      #pragma unroll
      for (int n = 0; n < 8; ++n){
        size_t off = eFD + (size_t)(ocol + n*16) * F_ + f0 + ks*32 + lg*8;
        bfr[n] = loadw8<B16>(wpj, off);
      }
      #pragma unroll
      for (int m = 0; m < 4; ++m){
        int row = m*16 + lr;
        short8 afrag = *reinterpret_cast<const short8*>(smem + H_OFF + row*H_STRIDE + (ks*32 + lg*8)*2);
        #pragma unroll
        for (int n = 0; n < 8; ++n)
          yacc[m][n] = __builtin_amdgcn_mfma_f32_16x16x32_bf16(afrag, bfr[n], yacc[m][n], 0, 0, 0);
      }
    }
  }

  // ---- epilogue: + b_proj, * routing weight, accumulate into out ----
  float bp[8];
  #pragma unroll
  for (int n = 0; n < 8; ++n) bp[n] = bpj[e*D_ + ocol + n*16];
  #pragma unroll
  for (int m = 0; m < 4; ++m){
    #pragma unroll
    for (int i = 0; i < 4; ++i){
      int rr = m*16 + lg*4 + i;
      int t = s_tok[rr];
      float wgt = s_w[rr];
      float* orow = out + (size_t)t * D_;
      #pragma unroll
      for (int n = 0; n < 8; ++n)
        unsafeAtomicAdd(&orow[ocol + n*16], (yacc[m][n][i] + bp[n]) * wgt);
    }
  }
}

extern "C" void kernel_launch(void* const* d_in, const int* in_sizes, int n_in,
                              void* d_out, int out_size, void* d_ws, size_t ws_size,
                              hipStream_t stream){
  const float* x   = (const float*)d_in[0];
  const float* gw  = (const float*)d_in[1];
  const float* wfc = (const float*)d_in[2];
  const float* bfc = (const float*)d_in[3];
  const float* wpj = (const float*)d_in[4];
  const float* bpj = (const float*)d_in[5];
  float* out = (float*)d_out;

  int T = in_sizes[0] / D_;        // 8192
  int nAssign = T * K_;
  int nSlots = nAssign + E_ * BM;  // padded per-expert regions upper bound

  char* ws = (char*)d_ws;
  size_t o = 0;
  int*   tidx    = (int*)(ws + o); o += (size_t)nAssign * 4;
  float* tw      = (float*)(ws + o); o += (size_t)nAssign * 4;
  int*   counts  = (int*)(ws + o); o += 256;
  int*   cursors = (int*)(ws + o); o += 256;
  int*   aligned = (int*)(ws + o); o += 256;
  int*   rowTok  = (int*)(ws + o); o += (size_t)nSlots * 4;
  float* rowW    = (float*)(ws + o); o += (size_t)nSlots * 4;
  o = (o + 255) & ~(size_t)255;
  size_t wbytes = (size_t)E_ * F_ * D_ * 2;
  bool b16 = (ws_size >= o + 2 * wbytes);
  __hip_bfloat16* wfc16 = (__hip_bfloat16*)(ws + o);
  __hip_bfloat16* wpj16 = (__hip_bfloat16*)(ws + o + wbytes);

  hipMemsetAsync(d_out, 0, (size_t)out_size * 4, stream);
  init_kernel<<<(nSlots + 255)/256, 256, 0, stream>>>(rowTok, rowW, counts, cursors, nSlots);
  gate_kernel<<<(T + 3)/4, 256, 0, stream>>>(x, gw, tidx, tw, counts, T);
  scan_kernel<<<1, 64, 0, stream>>>(counts, aligned);
  scatter_kernel<<<(T + 255)/256, 256, 0, stream>>>(tidx, tw, aligned, cursors, rowTok, rowW, T);

  int maxTiles = nSlots / BM;      // 264
  if (b16){
    int n4 = E_ * F_ * D_ / 4;
    cvtw_kernel<<<2048, 256, 0, stream>>>(wfc, wfc16, n4);
    cvtw_kernel<<<2048, 256, 0, stream>>>(wpj, wpj16, n4);
    hipFuncSetAttribute(reinterpret_cast<const void*>(&moe_tile_kernel<true>),
                        hipFuncAttributeMaxDynamicSharedMemorySize, SMEM_BYTES);
    moe_tile_kernel<true><<<maxTiles, 512, SMEM_BYTES, stream>>>(
        x, (const void*)wfc16, (const void*)wpj16, bfc, bpj, rowTok, rowW, aligned, out);
  } else {
    hipFuncSetAttribute(reinterpret_cast<const void*>(&moe_tile_kernel<false>),
                        hipFuncAttributeMaxDynamicSharedMemorySize, SMEM_BYTES);
    moe_tile_kernel<false><<<maxTiles, 512, SMEM_BYTES, stream>>>(
        x, (const void*)wfc, (const void*)wpj, bfc, bpj, rowTok, rowW, aligned, out);
  }
}

// Round 2
// 866.127 us; speedup vs baseline: 3.2031x; 3.2031x over previous
//
#include <hip/hip_runtime.h>
#include <hip/hip_bf16.h>

#define E_ 8
#define D_ 1024
#define F_ 4096
#define K_ 2
#define BMR 128   // GEMM row-tile / per-expert alignment

typedef __attribute__((ext_vector_type(8))) short short8;
typedef __attribute__((ext_vector_type(4))) float f32x4;

__device__ __forceinline__ unsigned short f2bf(float f){
  union { __hip_bfloat16 h; unsigned short u; } c;
  c.h = __float2bfloat16(f);
  return c.u;
}

__device__ __forceinline__ short8 cvt8(float4 a, float4 b){
  short8 r;
  r[0]=(short)f2bf(a.x); r[1]=(short)f2bf(a.y); r[2]=(short)f2bf(a.z); r[3]=(short)f2bf(a.w);
  r[4]=(short)f2bf(b.x); r[5]=(short)f2bf(b.y); r[6]=(short)f2bf(b.z); r[7]=(short)f2bf(b.w);
  return r;
}

template<bool B16>
__device__ __forceinline__ short8 loadw8(const void* __restrict__ base, size_t off){
  if constexpr (B16) {
    return *reinterpret_cast<const short8*>(reinterpret_cast<const __hip_bfloat16*>(base) + off);
  } else {
    const float4* p = reinterpret_cast<const float4*>(reinterpret_cast<const float*>(base) + off);
    float4 a = p[0]; float4 b = p[1];
    return cvt8(a, b);
  }
}

__device__ __forceinline__ float gelu_f(float v){
  const float c0 = 0.7978845608028654f;   // sqrt(2/pi)
  float z = c0 * (v + 0.044715f * v * v * v);
  float e = __expf(2.0f * z);
  float t = 1.0f - 2.0f / (1.0f + e);     // tanh(z), stable for |z| large
  return 0.5f * v * (1.0f + t);
}

__device__ __forceinline__ void gload16(const void* gsrc, void* ldst){
  __builtin_amdgcn_global_load_lds(
      (const __attribute__((address_space(1))) unsigned int*)gsrc,
      (__attribute__((address_space(3))) unsigned int*)ldst, 16, 0, 0);
}

// ---------------- gating ----------------
__global__ void gate_kernel(const float* __restrict__ x, const float* __restrict__ gw,
                            int* __restrict__ tidx, float* __restrict__ tw,
                            int* __restrict__ counts, int T){
  int wid = threadIdx.x >> 6, lane = threadIdx.x & 63;
  int t = blockIdx.x * 4 + wid;
  if (t >= T) return;
  const float* xr = x + (size_t)t * D_;
  double acc[E_];
  #pragma unroll
  for (int e = 0; e < E_; ++e) acc[e] = 0.0;
  #pragma unroll
  for (int j = 0; j < 16; ++j){
    float xv = xr[j*64 + lane];
    #pragma unroll
    for (int e = 0; e < E_; ++e)
      acc[e] += (double)xv * (double)gw[e*D_ + j*64 + lane];
  }
  #pragma unroll
  for (int e = 0; e < E_; ++e){
    #pragma unroll
    for (int off = 32; off >= 1; off >>= 1)
      acc[e] += __shfl_xor(acc[e], off);
  }
  if (lane == 0){
    float l[E_];
    #pragma unroll
    for (int e = 0; e < E_; ++e) l[e] = (float)acc[e];
    int i0 = 0; float v0 = l[0];
    #pragma unroll
    for (int e = 1; e < E_; ++e) if (l[e] > v0){ v0 = l[e]; i0 = e; }
    int i1 = -1; float v1 = -1e30f;
    #pragma unroll
    for (int e = 0; e < E_; ++e) if (e != i0 && l[e] > v1){ v1 = l[e]; i1 = e; }
    float e1 = expf(v1 - v0);
    float s = 1.0f + e1;
    tidx[2*t] = i0; tidx[2*t+1] = i1;
    tw[2*t] = 1.0f / s; tw[2*t+1] = e1 / s;
    atomicAdd(&counts[i0], 1);
    atomicAdd(&counts[i1], 1);
  }
}

__global__ void init_kernel(int* rowTok, float* rowW, int* counts, int* cursors, int nSlots){
  int i = blockIdx.x * blockDim.x + threadIdx.x;
  if (i < nSlots){ rowTok[i] = 0; rowW[i] = 0.0f; }
  if (i < E_){ counts[i] = 0; cursors[i] = 0; }
}

__global__ void scan_kernel(const int* counts, int* aligned){
  if (threadIdx.x == 0 && blockIdx.x == 0){
    int s = 0;
    for (int e = 0; e < E_; ++e){ aligned[e] = s; s += ((counts[e] + BMR - 1) / BMR) * BMR; }
    aligned[E_] = s;
  }
}

__global__ void scatter_kernel(const int* __restrict__ tidx, const float* __restrict__ tw,
                               const int* __restrict__ aligned, int* cursors,
                               int* __restrict__ rowTok, float* __restrict__ rowW, int T){
  int t = blockIdx.x * blockDim.x + threadIdx.x;
  if (t >= T) return;
  for (int k = 0; k < K_; ++k){
    int e = tidx[2*t + k];
    int pos = aligned[e] + atomicAdd(&cursors[e], 1);
    rowTok[pos] = t;
    rowW[pos] = tw[2*t + k];
  }
}

// ---------------- gathered A build (fp32 x -> bf16 rows by slot) ----------------
__global__ void gather_kernel(const float* __restrict__ x, const int* __restrict__ rowTok,
                              __hip_bfloat16* __restrict__ Abuf){
  int slot = blockIdx.x;
  int t = rowTok[slot];
  const float4* src = reinterpret_cast<const float4*>(x + (size_t)t * D_);
  uint2* dst = reinterpret_cast<uint2*>(reinterpret_cast<unsigned short*>(Abuf) + (size_t)slot * D_);
  float4 v = src[threadIdx.x];
  uint2 p;
  p.x = (unsigned)f2bf(v.x) | ((unsigned)f2bf(v.y) << 16);
  p.y = (unsigned)f2bf(v.z) | ((unsigned)f2bf(v.w) << 16);
  dst[threadIdx.x] = p;
}

// ---------------- weight fp32 -> bf16 ----------------
__global__ void cvtw_kernel(const float* __restrict__ src, __hip_bfloat16* __restrict__ dst, int n4){
  int stride = gridDim.x * blockDim.x;
  for (int i = blockIdx.x * blockDim.x + threadIdx.x; i < n4; i += stride){
    float4 v = reinterpret_cast<const float4*>(src)[i];
    uint2 p;
    p.x = (unsigned)f2bf(v.x) | ((unsigned)f2bf(v.y) << 16);
    p.y = (unsigned)f2bf(v.z) | ((unsigned)f2bf(v.w) << 16);
    reinterpret_cast<uint2*>(dst)[i] = p;
  }
}

// ---------------- 128x128 GEMM (m97 structure), PH1: H=gelu(A wfc^T+b); PH2: out+=w*(H wproj^T+b) ----------------
template<bool WB16, bool PH1>
__global__ __launch_bounds__(256, 3) void gemm_kernel(
    const __hip_bfloat16* __restrict__ Abuf,   // [rows][KA] bf16
    const void* __restrict__ W,                // [E][NT][KA] bf16 or fp32
    const float* __restrict__ bias,            // [E][NT]
    const int* __restrict__ aligned,
    __hip_bfloat16* __restrict__ Hout,         // PH1 out
    const int* __restrict__ rowTok, const float* __restrict__ rowW,
    float* __restrict__ out)                   // PH2 out
{
  constexpr int KA = PH1 ? D_ : F_;
  constexpr int NT = PH1 ? F_ : D_;
  constexpr int NK = KA / 64;

  __shared__ char sA[128*128];
  __shared__ char sB[128*128];

  int rowBase = blockIdx.x * BMR;
  if (rowBase >= aligned[E_]) return;
  int e = 0;
  #pragma unroll
  for (int i = 1; i < E_; ++i) if (rowBase >= aligned[i]) e = i;

  int nBase = blockIdx.y * 128;
  const int tid = threadIdx.x;
  const int wid = tid >> 6, lane = tid & 63;
  const int lr = lane & 15, lg = lane >> 4;
  const int wr = wid >> 1, wc = wid & 1;

  const unsigned short* Wb = (const unsigned short*)W;
  const float* Wf = (const float*)W;
  const size_t Wrow0 = (size_t)e * NT + nBase;

  f32x4 acc[4][4];
  #pragma unroll
  for (int m = 0; m < 4; ++m)
    #pragma unroll
    for (int n = 0; n < 4; ++n) acc[m][n] = (f32x4){0.f,0.f,0.f,0.f};

  for (int kt = 0; kt < NK; ++kt){
    int k0 = kt * 64;
    // ---- stage A tile via global_load_lds (linear dest, inverse-swizzled source) ----
    #pragma unroll
    for (int i = 0; i < 4; ++i){
      int flat = i*4096 + wid*1024 + lane*16;
      int row  = flat >> 7;
      int colb = flat & 127;
      int scol = colb ^ ((row & 7) << 4);
      const char* src = (const char*)(Abuf + (size_t)(rowBase + row) * KA + k0) + scol;
      gload16(src, sA + i*4096 + wid*1024);
    }
    // ---- stage B tile ----
    if constexpr (WB16){
      #pragma unroll
      for (int i = 0; i < 4; ++i){
        int flat = i*4096 + wid*1024 + lane*16;
        int row  = flat >> 7;
        int colb = flat & 127;
        int scol = colb ^ ((row & 7) << 4);
        const char* src = (const char*)(Wb + (Wrow0 + row) * KA + k0) + scol;
        gload16(src, sB + i*4096 + wid*1024);
      }
    } else {
      // reg-stage fp32 -> bf16, write-side swizzle
      #pragma unroll
      for (int i = 0; i < 8; ++i){
        int f4  = i*256 + tid;      // float4 index: 128 rows x 16 per row
        int row = f4 >> 4;
        int c4  = f4 & 15;
        float4 v = *reinterpret_cast<const float4*>(Wf + (Wrow0 + row) * KA + k0 + c4*4);
        uint2 p;
        p.x = (unsigned)f2bf(v.x) | ((unsigned)f2bf(v.y) << 16);
        p.y = (unsigned)f2bf(v.z) | ((unsigned)f2bf(v.w) << 16);
        int byte = row*128 + c4*8;
        *reinterpret_cast<uint2*>(sB + (byte ^ ((row & 7) << 4))) = p;
      }
    }
    __syncthreads();
    // ---- compute ----
    #pragma unroll
    for (int ks = 0; ks < 2; ++ks){
      short8 a[4], b[4];
      #pragma unroll
      for (int m = 0; m < 4; ++m){
        int row = wr*64 + m*16 + lr;
        a[m] = *reinterpret_cast<const short8*>(sA + row*128 + ((ks*64 + lg*16) ^ ((row & 7) << 4)));
      }
      #pragma unroll
      for (int n = 0; n < 4; ++n){
        int row = wc*64 + n*16 + lr;
        b[n] = *reinterpret_cast<const short8*>(sB + row*128 + ((ks*64 + lg*16) ^ ((row & 7) << 4)));
      }
      #pragma unroll
      for (int m = 0; m < 4; ++m)
        #pragma unroll
        for (int n = 0; n < 4; ++n)
          acc[m][n] = __builtin_amdgcn_mfma_f32_16x16x32_bf16(a[m], b[n], acc[m][n], 0, 0, 0);
    }
    __syncthreads();
  }

  int colBase = nBase + wc*64;
  if constexpr (PH1){
    #pragma unroll
    for (int m = 0; m < 4; ++m){
      int growb = rowBase + wr*64 + m*16 + lg*4;
      #pragma unroll
      for (int i = 0; i < 4; ++i){
        unsigned short* hrow = reinterpret_cast<unsigned short*>(Hout) + (size_t)(growb + i) * F_;
        #pragma unroll
        for (int n = 0; n < 4; ++n){
          int gcol = colBase + n*16 + lr;
          float v = gelu_f(acc[m][n][i] + bias[e*F_ + gcol]);
          hrow[gcol] = f2bf(v);
        }
      }
    }
  } else {
    #pragma unroll
    for (int m = 0; m < 4; ++m){
      #pragma unroll
      for (int i = 0; i < 4; ++i){
        int grow = rowBase + wr*64 + m*16 + lg*4 + i;
        int t = rowTok[grow];
        float w = rowW[grow];
        float* orow = out + (size_t)t * D_;
        #pragma unroll
        for (int n = 0; n < 4; ++n){
          int gcol = colBase + n*16 + lr;
          unsafeAtomicAdd(&orow[gcol], (acc[m][n][i] + bias[e*D_ + gcol]) * w);
        }
      }
    }
  }
}

// ---------------- round-1 fused fallback (only used if ws is tiny) ----------------
#define H_OFF (64*2048)
#define H_STRIDE 272
#define TOK_OFF (H_OFF + 64*H_STRIDE)
#define WV_OFF (TOK_OFF + 256)
#define SMEM_BYTES (WV_OFF + 256)

template<bool B16>
__global__ __launch_bounds__(512) void moe_tile_kernel(
    const float* __restrict__ x,
    const void* __restrict__ wfc, const void* __restrict__ wpj,
    const float* __restrict__ bfc, const float* __restrict__ bpj,
    const int* __restrict__ rowTok, const float* __restrict__ rowW,
    const int* __restrict__ aligned, float* __restrict__ out)
{
  extern __shared__ char smem[];
  int tb = blockIdx.x * 64;
  if (tb >= aligned[E_]) return;
  int e = 0;
  #pragma unroll
  for (int i = 1; i < E_; ++i) if (tb >= aligned[i]) e = i;

  const int tid = threadIdx.x;
  const int wid = tid >> 6, lane = tid & 63;
  const int lr = lane & 15, lg = lane >> 4;

  int* s_tok = (int*)(smem + TOK_OFF);
  float* s_w = (float*)(smem + WV_OFF);
  if (tid < 64){ s_tok[tid] = rowTok[tb + tid]; s_w[tid] = rowW[tb + tid]; }
  __syncthreads();

  for (int r = wid; r < 64; r += 8){
    const float4* src = reinterpret_cast<const float4*>(x + (size_t)s_tok[r] * D_);
    int sw = (r & 7) << 4;
    #pragma unroll
    for (int i = 0; i < 4; ++i){
      float4 v = src[i*64 + lane];
      uint2 p;
      p.x = (unsigned)f2bf(v.x) | ((unsigned)f2bf(v.y) << 16);
      p.y = (unsigned)f2bf(v.z) | ((unsigned)f2bf(v.w) << 16);
      int byte = r*2048 + (i*64 + lane)*8;
      *reinterpret_cast<uint2*>(smem + (byte ^ sw)) = p;
    }
  }
  __syncthreads();

  const size_t eFD = (size_t)e * F_ * D_;
  const int fcol = wid*16 + lr;
  const int ocol = wid*128 + lr;

  f32x4 yacc[4][8];
  #pragma unroll
  for (int m = 0; m < 4; ++m)
    #pragma unroll
    for (int n = 0; n < 8; ++n) yacc[m][n] = (f32x4){0.f,0.f,0.f,0.f};

  for (int fc = 0; fc < F_/128; ++fc){
    int f0 = fc * 128;
    f32x4 hacc[4];
    #pragma unroll
    for (int m = 0; m < 4; ++m) hacc[m] = (f32x4){0.f,0.f,0.f,0.f};
    size_t wfc_off = eFD + (size_t)(f0 + fcol) * D_ + lg*8;
    for (int ks = 0; ks < 32; ++ks){
      short8 bfrag = loadw8<B16>(wfc, wfc_off + ks*32);
      #pragma unroll
      for (int m = 0; m < 4; ++m){
        int row = m*16 + lr;
        int byte = (row*2048 + (ks*32 + lg*8)*2) ^ ((row & 7) << 4);
        short8 afrag = *reinterpret_cast<const short8*>(smem + byte);
        hacc[m] = __builtin_amdgcn_mfma_f32_16x16x32_bf16(afrag, bfrag, hacc[m], 0, 0, 0);
      }
    }
    float bias = bfc[e*F_ + f0 + fcol];
    __syncthreads();
    #pragma unroll
    for (int m = 0; m < 4; ++m){
      #pragma unroll
      for (int i = 0; i < 4; ++i){
        float g = gelu_f(hacc[m][i] + bias);
        int hrow = m*16 + lg*4 + i;
        *reinterpret_cast<unsigned short*>(smem + H_OFF + hrow*H_STRIDE + fcol*2) = f2bf(g);
      }
    }
    __syncthreads();
    #pragma unroll
    for (int ks = 0; ks < 4; ++ks){
      short8 bfr[8];
      #pragma unroll
      for (int n = 0; n < 8; ++n){
        size_t off = eFD + (size_t)(ocol + n*16) * F_ + f0 + ks*32 + lg*8;
        bfr[n] = loadw8<B16>(wpj, off);
      }
      #pragma unroll
      for (int m = 0; m < 4; ++m){
        int row = m*16 + lr;
        short8 afrag = *reinterpret_cast<const short8*>(smem + H_OFF + row*H_STRIDE + (ks*32 + lg*8)*2);
        #pragma unroll
        for (int n = 0; n < 8; ++n)
          yacc[m][n] = __builtin_amdgcn_mfma_f32_16x16x32_bf16(afrag, bfr[n], yacc[m][n], 0, 0, 0);
      }
    }
  }

  float bp[8];
  #pragma unroll
  for (int n = 0; n < 8; ++n) bp[n] = bpj[e*D_ + ocol + n*16];
  #pragma unroll
  for (int m = 0; m < 4; ++m){
    #pragma unroll
    for (int i = 0; i < 4; ++i){
      int rr = m*16 + lg*4 + i;
      int t = s_tok[rr];
      float wgt = s_w[rr];
      float* orow = out + (size_t)t * D_;
      #pragma unroll
      for (int n = 0; n < 8; ++n)
        unsafeAtomicAdd(&orow[ocol + n*16], (yacc[m][n][i] + bp[n]) * wgt);
    }
  }
}

extern "C" void kernel_launch(void* const* d_in, const int* in_sizes, int n_in,
                              void* d_out, int out_size, void* d_ws, size_t ws_size,
                              hipStream_t stream){
  const float* x   = (const float*)d_in[0];
  const float* gw  = (const float*)d_in[1];
  const float* wfc = (const float*)d_in[2];
  const float* bfc = (const float*)d_in[3];
  const float* wpj = (const float*)d_in[4];
  const float* bpj = (const float*)d_in[5];
  float* out = (float*)d_out;

  int T = in_sizes[0] / D_;            // 8192
  int nAssign = T * K_;
  int nSlotsMax = nAssign + E_ * BMR;  // 17408
  int rowTilesMax = nSlotsMax / BMR;   // 136

  char* ws = (char*)d_ws;
  size_t o = 0;
  int*   tidx    = (int*)(ws + o); o += (size_t)nAssign * 4;
  float* tw      = (float*)(ws + o); o += (size_t)nAssign * 4;
  int*   counts  = (int*)(ws + o); o += 256;
  int*   cursors = (int*)(ws + o); o += 256;
  int*   aligned = (int*)(ws + o); o += 256;
  int*   rowTok  = (int*)(ws + o); o += (size_t)nSlotsMax * 4;
  float* rowW    = (float*)(ws + o); o += (size_t)nSlotsMax * 4;
  o = (o + 255) & ~(size_t)255;
  size_t o_rout = o;

  size_t abytes = (size_t)nSlotsMax * D_ * 2;
  size_t hbytes = (size_t)nSlotsMax * F_ * 2;
  size_t wbytes = (size_t)E_ * F_ * D_ * 2;

  __hip_bfloat16* Abuf = (__hip_bfloat16*)(ws + o); o += abytes;
  __hip_bfloat16* Hbuf = (__hip_bfloat16*)(ws + o); o += hbytes;
  size_t o_nw = o;
  __hip_bfloat16* wfc16 = (__hip_bfloat16*)(ws + o_nw);
  __hip_bfloat16* wpj16 = (__hip_bfloat16*)(ws + o_nw + wbytes);

  bool twoPass = (ws_size >= o_nw);                 // ~171 MB
  bool wB16    = (ws_size >= o_nw + 2 * wbytes);    // ~299 MB

  hipMemsetAsync(d_out, 0, (size_t)out_size * 4, stream);
  init_kernel<<<(nSlotsMax + 255)/256, 256, 0, stream>>>(rowTok, rowW, counts, cursors, nSlotsMax);
  gate_kernel<<<(T + 3)/4, 256, 0, stream>>>(x, gw, tidx, tw, counts, T);
  scan_kernel<<<1, 64, 0, stream>>>(counts, aligned);
  scatter_kernel<<<(T + 255)/256, 256, 0, stream>>>(tidx, tw, aligned, cursors, rowTok, rowW, T);

  if (twoPass){
    gather_kernel<<<nSlotsMax, 256, 0, stream>>>(x, rowTok, Abuf);
    if (wB16){
      int n4 = E_ * F_ * D_ / 4;
      cvtw_kernel<<<2048, 256, 0, stream>>>(wfc, wfc16, n4);
      cvtw_kernel<<<2048, 256, 0, stream>>>(wpj, wpj16, n4);
      gemm_kernel<true, true><<<dim3(rowTilesMax, F_/128), 256, 0, stream>>>(
          Abuf, (const void*)wfc16, bfc, aligned, Hbuf, rowTok, rowW, out);
      gemm_kernel<true, false><<<dim3(rowTilesMax, D_/128), 256, 0, stream>>>(
          Hbuf, (const void*)wpj16, bpj, aligned, (__hip_bfloat16*)nullptr, rowTok, rowW, out);
    } else {
      gemm_kernel<false, true><<<dim3(rowTilesMax, F_/128), 256, 0, stream>>>(
          Abuf, (const void*)wfc, bfc, aligned, Hbuf, rowTok, rowW, out);
      gemm_kernel<false, false><<<dim3(rowTilesMax, D_/128), 256, 0, stream>>>(
          Hbuf, (const void*)wpj, bpj, aligned, (__hip_bfloat16*)nullptr, rowTok, rowW, out);
    }
  } else {
    // emergency fallback: round-1 fused kernel
    int fusedTiles = nSlotsMax / 64;
    bool b16 = (ws_size >= o_rout + 2 * wbytes);
    __hip_bfloat16* fwfc16 = (__hip_bfloat16*)(ws + o_rout);
    __hip_bfloat16* fwpj16 = (__hip_bfloat16*)(ws + o_rout + wbytes);
    if (b16){
      int n4 = E_ * F_ * D_ / 4;
      cvtw_kernel<<<2048, 256, 0, stream>>>(wfc, fwfc16, n4);
      cvtw_kernel<<<2048, 256, 0, stream>>>(wpj, fwpj16, n4);
      hipFuncSetAttribute(reinterpret_cast<const void*>(&moe_tile_kernel<true>),
                          hipFuncAttributeMaxDynamicSharedMemorySize, SMEM_BYTES);
      moe_tile_kernel<true><<<fusedTiles, 512, SMEM_BYTES, stream>>>(
          x, (const void*)fwfc16, (const void*)fwpj16, bfc, bpj, rowTok, rowW, aligned, out);
    } else {
      hipFuncSetAttribute(reinterpret_cast<const void*>(&moe_tile_kernel<false>),
                          hipFuncAttributeMaxDynamicSharedMemorySize, SMEM_BYTES);
      moe_tile_kernel<false><<<fusedTiles, 512, SMEM_BYTES, stream>>>(
          x, (const void*)wfc, (const void*)wpj, bfc, bpj, rowTok, rowW, aligned, out);
    }
  }
}

// Round 3
// 747.375 us; speedup vs baseline: 3.7121x; 1.1589x over previous
//
#include <hip/hip_runtime.h>
#include <hip/hip_bf16.h>

#define E_ 8
#define D_ 1024
#define F_ 4096
#define K_ 2
#define BMR 128   // GEMM row-tile / per-expert alignment

typedef __attribute__((ext_vector_type(8))) short short8;
typedef __attribute__((ext_vector_type(4))) float f32x4;

__device__ __forceinline__ unsigned short f2bf(float f){
  union { __hip_bfloat16 h; unsigned short u; } c;
  c.h = __float2bfloat16(f);
  return c.u;
}

__device__ __forceinline__ float bf2f(unsigned u){
  union { float f; unsigned u; } c;
  c.u = u << 16;
  return c.f;
}

__device__ __forceinline__ short8 cvt8(float4 a, float4 b){
  short8 r;
  r[0]=(short)f2bf(a.x); r[1]=(short)f2bf(a.y); r[2]=(short)f2bf(a.z); r[3]=(short)f2bf(a.w);
  r[4]=(short)f2bf(b.x); r[5]=(short)f2bf(b.y); r[6]=(short)f2bf(b.z); r[7]=(short)f2bf(b.w);
  return r;
}

template<bool B16>
__device__ __forceinline__ short8 loadw8(const void* __restrict__ base, size_t off){
  if constexpr (B16) {
    return *reinterpret_cast<const short8*>(reinterpret_cast<const __hip_bfloat16*>(base) + off);
  } else {
    const float4* p = reinterpret_cast<const float4*>(reinterpret_cast<const float*>(base) + off);
    float4 a = p[0]; float4 b = p[1];
    return cvt8(a, b);
  }
}

__device__ __forceinline__ float gelu_f(float v){
  const float c0 = 0.7978845608028654f;   // sqrt(2/pi)
  float z = c0 * (v + 0.044715f * v * v * v);
  float e = __expf(2.0f * z);
  float t = 1.0f - 2.0f / (1.0f + e);     // tanh(z), stable for |z| large
  return 0.5f * v * (1.0f + t);
}

__device__ __forceinline__ void gload16(const void* gsrc, void* ldst){
  __builtin_amdgcn_global_load_lds(
      (const __attribute__((address_space(1))) unsigned int*)gsrc,
      (__attribute__((address_space(3))) unsigned int*)ldst, 16, 0, 0);
}

// ---------------- gating ----------------
__global__ void gate_kernel(const float* __restrict__ x, const float* __restrict__ gw,
                            int* __restrict__ tidx, float* __restrict__ tw,
                            int* __restrict__ counts, int T){
  int wid = threadIdx.x >> 6, lane = threadIdx.x & 63;
  int t = blockIdx.x * 4 + wid;
  if (t >= T) return;
  const float* xr = x + (size_t)t * D_;
  double acc[E_];
  #pragma unroll
  for (int e = 0; e < E_; ++e) acc[e] = 0.0;
  #pragma unroll
  for (int j = 0; j < 16; ++j){
    float xv = xr[j*64 + lane];
    #pragma unroll
    for (int e = 0; e < E_; ++e)
      acc[e] += (double)xv * (double)gw[e*D_ + j*64 + lane];
  }
  #pragma unroll
  for (int e = 0; e < E_; ++e){
    #pragma unroll
    for (int off = 32; off >= 1; off >>= 1)
      acc[e] += __shfl_xor(acc[e], off);
  }
  if (lane == 0){
    float l[E_];
    #pragma unroll
    for (int e = 0; e < E_; ++e) l[e] = (float)acc[e];
    int i0 = 0; float v0 = l[0];
    #pragma unroll
    for (int e = 1; e < E_; ++e) if (l[e] > v0){ v0 = l[e]; i0 = e; }
    int i1 = -1; float v1 = -1e30f;
    #pragma unroll
    for (int e = 0; e < E_; ++e) if (e != i0 && l[e] > v1){ v1 = l[e]; i1 = e; }
    float e1 = expf(v1 - v0);
    float s = 1.0f + e1;
    tidx[2*t] = i0; tidx[2*t+1] = i1;
    tw[2*t] = 1.0f / s; tw[2*t+1] = e1 / s;
    atomicAdd(&counts[i0], 1);
    atomicAdd(&counts[i1], 1);
  }
}

__global__ void init_kernel(int* rowTok, float* rowW, int* counts, int* cursors, int nSlots){
  int i = blockIdx.x * blockDim.x + threadIdx.x;
  if (i < nSlots){ rowTok[i] = 0; rowW[i] = 0.0f; }
  if (i < E_){ counts[i] = 0; cursors[i] = 0; }
}

__global__ void scan_kernel(const int* counts, int* aligned){
  if (threadIdx.x == 0 && blockIdx.x == 0){
    int s = 0;
    for (int e = 0; e < E_; ++e){ aligned[e] = s; s += ((counts[e] + BMR - 1) / BMR) * BMR; }
    aligned[E_] = s;
  }
}

__global__ void scatter_kernel(const int* __restrict__ tidx, const float* __restrict__ tw,
                               const int* __restrict__ aligned, int* cursors,
                               int* __restrict__ rowTok, float* __restrict__ rowW,
                               int* __restrict__ tokSlot, int T){
  int t = blockIdx.x * blockDim.x + threadIdx.x;
  if (t >= T) return;
  for (int k = 0; k < K_; ++k){
    int e = tidx[2*t + k];
    int pos = aligned[e] + atomicAdd(&cursors[e], 1);
    rowTok[pos] = t;
    rowW[pos] = tw[2*t + k];
    tokSlot[2*t + k] = pos;
  }
}

// ---------------- gathered A build (fp32 x -> bf16 rows by slot) ----------------
__global__ void gather_kernel(const float* __restrict__ x, const int* __restrict__ rowTok,
                              __hip_bfloat16* __restrict__ Abuf){
  int slot = blockIdx.x;
  int t = rowTok[slot];
  const float4* src = reinterpret_cast<const float4*>(x + (size_t)t * D_);
  uint2* dst = reinterpret_cast<uint2*>(reinterpret_cast<unsigned short*>(Abuf) + (size_t)slot * D_);
  float4 v = src[threadIdx.x];
  uint2 p;
  p.x = (unsigned)f2bf(v.x) | ((unsigned)f2bf(v.y) << 16);
  p.y = (unsigned)f2bf(v.z) | ((unsigned)f2bf(v.w) << 16);
  dst[threadIdx.x] = p;
}

// ---------------- weight fp32 -> bf16 ----------------
__global__ void cvtw_kernel(const float* __restrict__ src, __hip_bfloat16* __restrict__ dst, int n4){
  int stride = gridDim.x * blockDim.x;
  for (int i = blockIdx.x * blockDim.x + threadIdx.x; i < n4; i += stride){
    float4 v = reinterpret_cast<const float4*>(src)[i];
    uint2 p;
    p.x = (unsigned)f2bf(v.x) | ((unsigned)f2bf(v.y) << 16);
    p.y = (unsigned)f2bf(v.z) | ((unsigned)f2bf(v.w) << 16);
    reinterpret_cast<uint2*>(dst)[i] = p;
  }
}

// ---------------- final combine: out[t] = sum_k w_k * (Y[slot_k] + b_proj[e_k]) ----------------
__global__ void combine_kernel(const unsigned short* __restrict__ Ybuf,
                               const int* __restrict__ tidx, const float* __restrict__ tw,
                               const int* __restrict__ tokSlot,
                               const float* __restrict__ bpj,
                               float* __restrict__ out){
  int t = blockIdx.x;
  int d = threadIdx.x * 4;
  int e0 = tidx[2*t], e1 = tidx[2*t+1];
  float w0 = tw[2*t], w1 = tw[2*t+1];
  int s0 = tokSlot[2*t], s1 = tokSlot[2*t+1];
  uint2 ya = *reinterpret_cast<const uint2*>(Ybuf + (size_t)s0*D_ + d);
  uint2 yb = *reinterpret_cast<const uint2*>(Ybuf + (size_t)s1*D_ + d);
  float4 b0 = *reinterpret_cast<const float4*>(bpj + (size_t)e0*D_ + d);
  float4 b1 = *reinterpret_cast<const float4*>(bpj + (size_t)e1*D_ + d);
  float4 r;
  r.x = w0*(bf2f(ya.x & 0xffffu) + b0.x) + w1*(bf2f(yb.x & 0xffffu) + b1.x);
  r.y = w0*(bf2f(ya.x >> 16)     + b0.y) + w1*(bf2f(yb.x >> 16)     + b1.y);
  r.z = w0*(bf2f(ya.y & 0xffffu) + b0.z) + w1*(bf2f(yb.y & 0xffffu) + b1.z);
  r.w = w0*(bf2f(ya.y >> 16)     + b0.w) + w1*(bf2f(yb.y >> 16)     + b1.w);
  *reinterpret_cast<float4*>(out + (size_t)t*D_ + d) = r;
}

// ---------------- 128x128 GEMM (m97 structure, swapped-operand epilogue) ----------------
// PH1: H = gelu(A wfc^T + b) -> bf16 Hbuf[slot][F]
// PH2: Y = H wproj^T         -> bf16 Ybuf[slot][D]   (bias+route in combine)
template<bool WB16, bool PH1>
__global__ __launch_bounds__(256, 4) void gemm_kernel(
    const __hip_bfloat16* __restrict__ Abuf,   // [rows][KA] bf16
    const void* __restrict__ W,                // [E][NT][KA] bf16 or fp32
    const float* __restrict__ bias,            // [E][NT] (PH1 only)
    const int* __restrict__ aligned,
    unsigned short* __restrict__ Out16)        // PH1: Hbuf; PH2: Ybuf
{
  constexpr int KA = PH1 ? D_ : F_;
  constexpr int NT = PH1 ? F_ : D_;
  constexpr int NK = KA / 64;

  __shared__ char sA[128*128];
  __shared__ char sB[128*128];

  // grid: x = column tile (XCD-resident B panels), y = row tile
  int rowBase = blockIdx.y * BMR;
  if (rowBase >= aligned[E_]) return;
  int e = 0;
  #pragma unroll
  for (int i = 1; i < E_; ++i) if (rowBase >= aligned[i]) e = i;

  int nBase = blockIdx.x * 128;
  const int tid = threadIdx.x;
  const int wid = tid >> 6, lane = tid & 63;
  const int lr = lane & 15, lg = lane >> 4;
  const int wr = wid >> 1, wc = wid & 1;

  const unsigned short* Wb = (const unsigned short*)W;
  const float* Wf = (const float*)W;
  const size_t Wrow0 = (size_t)e * NT + nBase;

  f32x4 acc[4][4];
  #pragma unroll
  for (int m = 0; m < 4; ++m)
    #pragma unroll
    for (int n = 0; n < 4; ++n) acc[m][n] = (f32x4){0.f,0.f,0.f,0.f};

  for (int kt = 0; kt < NK; ++kt){
    int k0 = kt * 64;
    // ---- stage A tile via global_load_lds (linear dest, inverse-swizzled source) ----
    #pragma unroll
    for (int i = 0; i < 4; ++i){
      int flat = i*4096 + wid*1024 + lane*16;
      int row  = flat >> 7;
      int colb = flat & 127;
      int scol = colb ^ ((row & 7) << 4);
      const char* src = (const char*)(Abuf + (size_t)(rowBase + row) * KA + k0) + scol;
      gload16(src, sA + i*4096 + wid*1024);
    }
    // ---- stage B tile ----
    if constexpr (WB16){
      #pragma unroll
      for (int i = 0; i < 4; ++i){
        int flat = i*4096 + wid*1024 + lane*16;
        int row  = flat >> 7;
        int colb = flat & 127;
        int scol = colb ^ ((row & 7) << 4);
        const char* src = (const char*)(Wb + (Wrow0 + row) * KA + k0) + scol;
        gload16(src, sB + i*4096 + wid*1024);
      }
    } else {
      // reg-stage fp32 -> bf16, write-side swizzle
      #pragma unroll
      for (int i = 0; i < 8; ++i){
        int f4  = i*256 + tid;      // float4 index: 128 rows x 16 per row
        int row = f4 >> 4;
        int c4  = f4 & 15;
        float4 v = *reinterpret_cast<const float4*>(Wf + (Wrow0 + row) * KA + k0 + c4*4);
        uint2 p;
        p.x = (unsigned)f2bf(v.x) | ((unsigned)f2bf(v.y) << 16);
        p.y = (unsigned)f2bf(v.z) | ((unsigned)f2bf(v.w) << 16);
        int byte = row*128 + c4*8;
        *reinterpret_cast<uint2*>(sB + (byte ^ ((row & 7) << 4))) = p;
      }
    }
    __syncthreads();
    // ---- compute (swapped operands: thread holds 4 contiguous output cols) ----
    #pragma unroll
    for (int ks = 0; ks < 2; ++ks){
      short8 a[4], b[4];
      #pragma unroll
      for (int m = 0; m < 4; ++m){
        int row = wr*64 + m*16 + lr;
        a[m] = *reinterpret_cast<const short8*>(sA + row*128 + ((ks*64 + lg*16) ^ ((row & 7) << 4)));
      }
      #pragma unroll
      for (int n = 0; n < 4; ++n){
        int row = wc*64 + n*16 + lr;
        b[n] = *reinterpret_cast<const short8*>(sB + row*128 + ((ks*64 + lg*16) ^ ((row & 7) << 4)));
      }
      #pragma unroll
      for (int m = 0; m < 4; ++m)
        #pragma unroll
        for (int n = 0; n < 4; ++n)
          acc[m][n] = __builtin_amdgcn_mfma_f32_16x16x32_bf16(b[n], a[m], acc[m][n], 0, 0, 0);
    }
    __syncthreads();
  }

  // epilogue: thread holds rows tkn = rowBase+wr*64+m*16+lr, cols colBase+n*16+lg*4+{0..3}
  int colBase = nBase + wc*64;
  if constexpr (PH1){
    #pragma unroll
    for (int n = 0; n < 4; ++n){
      int gc = colBase + n*16 + lg*4;
      float4 b4 = *reinterpret_cast<const float4*>(bias + (size_t)e*F_ + gc);
      #pragma unroll
      for (int m = 0; m < 4; ++m){
        int tkn = rowBase + wr*64 + m*16 + lr;
        uint2 p;
        p.x = (unsigned)f2bf(gelu_f(acc[m][n][0] + b4.x)) |
              ((unsigned)f2bf(gelu_f(acc[m][n][1] + b4.y)) << 16);
        p.y = (unsigned)f2bf(gelu_f(acc[m][n][2] + b4.z)) |
              ((unsigned)f2bf(gelu_f(acc[m][n][3] + b4.w)) << 16);
        *reinterpret_cast<uint2*>(Out16 + (size_t)tkn * F_ + gc) = p;
      }
    }
  } else {
    #pragma unroll
    for (int n = 0; n < 4; ++n){
      int gc = colBase + n*16 + lg*4;
      #pragma unroll
      for (int m = 0; m < 4; ++m){
        int slot = rowBase + wr*64 + m*16 + lr;
        uint2 p;
        p.x = (unsigned)f2bf(acc[m][n][0]) | ((unsigned)f2bf(acc[m][n][1]) << 16);
        p.y = (unsigned)f2bf(acc[m][n][2]) | ((unsigned)f2bf(acc[m][n][3]) << 16);
        *reinterpret_cast<uint2*>(Out16 + (size_t)slot * D_ + gc) = p;
      }
    }
  }
}

// ---------------- round-1 fused fallback (only used if ws is tiny) ----------------
#define H_OFF (64*2048)
#define H_STRIDE 272
#define TOK_OFF (H_OFF + 64*H_STRIDE)
#define WV_OFF (TOK_OFF + 256)
#define SMEM_BYTES (WV_OFF + 256)

template<bool B16>
__global__ __launch_bounds__(512) void moe_tile_kernel(
    const float* __restrict__ x,
    const void* __restrict__ wfc, const void* __restrict__ wpj,
    const float* __restrict__ bfc, const float* __restrict__ bpj,
    const int* __restrict__ rowTok, const float* __restrict__ rowW,
    const int* __restrict__ aligned, float* __restrict__ out)
{
  extern __shared__ char smem[];
  int tb = blockIdx.x * 64;
  if (tb >= aligned[E_]) return;
  int e = 0;
  #pragma unroll
  for (int i = 1; i < E_; ++i) if (tb >= aligned[i]) e = i;

  const int tid = threadIdx.x;
  const int wid = tid >> 6, lane = tid & 63;
  const int lr = lane & 15, lg = lane >> 4;

  int* s_tok = (int*)(smem + TOK_OFF);
  float* s_w = (float*)(smem + WV_OFF);
  if (tid < 64){ s_tok[tid] = rowTok[tb + tid]; s_w[tid] = rowW[tb + tid]; }
  __syncthreads();

  for (int r = wid; r < 64; r += 8){
    const float4* src = reinterpret_cast<const float4*>(x + (size_t)s_tok[r] * D_);
    int sw = (r & 7) << 4;
    #pragma unroll
    for (int i = 0; i < 4; ++i){
      float4 v = src[i*64 + lane];
      uint2 p;
      p.x = (unsigned)f2bf(v.x) | ((unsigned)f2bf(v.y) << 16);
      p.y = (unsigned)f2bf(v.z) | ((unsigned)f2bf(v.w) << 16);
      int byte = r*2048 + (i*64 + lane)*8;
      *reinterpret_cast<uint2*>(smem + (byte ^ sw)) = p;
    }
  }
  __syncthreads();

  const size_t eFD = (size_t)e * F_ * D_;
  const int fcol = wid*16 + lr;
  const int ocol = wid*128 + lr;

  f32x4 yacc[4][8];
  #pragma unroll
  for (int m = 0; m < 4; ++m)
    #pragma unroll
    for (int n = 0; n < 8; ++n) yacc[m][n] = (f32x4){0.f,0.f,0.f,0.f};

  for (int fc = 0; fc < F_/128; ++fc){
    int f0 = fc * 128;
    f32x4 hacc[4];
    #pragma unroll
    for (int m = 0; m < 4; ++m) hacc[m] = (f32x4){0.f,0.f,0.f,0.f};
    size_t wfc_off = eFD + (size_t)(f0 + fcol) * D_ + lg*8;
    for (int ks = 0; ks < 32; ++ks){
      short8 bfrag = loadw8<B16>(wfc, wfc_off + ks*32);
      #pragma unroll
      for (int m = 0; m < 4; ++m){
        int row = m*16 + lr;
        int byte = (row*2048 + (ks*32 + lg*8)*2) ^ ((row & 7) << 4);
        short8 afrag = *reinterpret_cast<const short8*>(smem + byte);
        hacc[m] = __builtin_amdgcn_mfma_f32_16x16x32_bf16(afrag, bfrag, hacc[m], 0, 0, 0);
      }
    }
    float bias = bfc[e*F_ + f0 + fcol];
    __syncthreads();
    #pragma unroll
    for (int m = 0; m < 4; ++m){
      #pragma unroll
      for (int i = 0; i < 4; ++i){
        float g = gelu_f(hacc[m][i] + bias);
        int hrow = m*16 + lg*4 + i;
        *reinterpret_cast<unsigned short*>(smem + H_OFF + hrow*H_STRIDE + fcol*2) = f2bf(g);
      }
    }
    __syncthreads();
    #pragma unroll
    for (int ks = 0; ks < 4; ++ks){
      short8 bfr[8];
      #pragma unroll
      for (int n = 0; n < 8; ++n){
        size_t off = eFD + (size_t)(ocol + n*16) * F_ + f0 + ks*32 + lg*8;
        bfr[n] = loadw8<B16>(wpj, off);
      }
      #pragma unroll
      for (int m = 0; m < 4; ++m){
        int row = m*16 + lr;
        short8 afrag = *reinterpret_cast<const short8*>(smem + H_OFF + row*H_STRIDE + (ks*32 + lg*8)*2);
        #pragma unroll
        for (int n = 0; n < 8; ++n)
          yacc[m][n] = __builtin_amdgcn_mfma_f32_16x16x32_bf16(afrag, bfr[n], yacc[m][n], 0, 0, 0);
      }
    }
  }

  float bp[8];
  #pragma unroll
  for (int n = 0; n < 8; ++n) bp[n] = bpj[e*D_ + ocol + n*16];
  #pragma unroll
  for (int m = 0; m < 4; ++m){
    #pragma unroll
    for (int i = 0; i < 4; ++i){
      int rr = m*16 + lg*4 + i;
      int t = s_tok[rr];
      float wgt = s_w[rr];
      float* orow = out + (size_t)t * D_;
      #pragma unroll
      for (int n = 0; n < 8; ++n)
        unsafeAtomicAdd(&orow[ocol + n*16], (yacc[m][n][i] + bp[n]) * wgt);
    }
  }
}

extern "C" void kernel_launch(void* const* d_in, const int* in_sizes, int n_in,
                              void* d_out, int out_size, void* d_ws, size_t ws_size,
                              hipStream_t stream){
  const float* x   = (const float*)d_in[0];
  const float* gw  = (const float*)d_in[1];
  const float* wfc = (const float*)d_in[2];
  const float* bfc = (const float*)d_in[3];
  const float* wpj = (const float*)d_in[4];
  const float* bpj = (const float*)d_in[5];
  float* out = (float*)d_out;

  int T = in_sizes[0] / D_;            // 8192
  int nAssign = T * K_;
  int nSlotsMax = nAssign + E_ * BMR;  // 17408
  int rowTilesMax = nSlotsMax / BMR;   // 136

  char* ws = (char*)d_ws;
  size_t o = 0;
  int*   tidx    = (int*)(ws + o); o += (size_t)nAssign * 4;
  float* tw      = (float*)(ws + o); o += (size_t)nAssign * 4;
  int*   counts  = (int*)(ws + o); o += 256;
  int*   cursors = (int*)(ws + o); o += 256;
  int*   aligned = (int*)(ws + o); o += 256;
  int*   rowTok  = (int*)(ws + o); o += (size_t)nSlotsMax * 4;
  float* rowW    = (float*)(ws + o); o += (size_t)nSlotsMax * 4;
  int*   tokSlot = (int*)(ws + o); o += (size_t)nAssign * 4;
  o = (o + 255) & ~(size_t)255;
  size_t o_rout = o;

  size_t abytes = (size_t)nSlotsMax * D_ * 2;   // Abuf; reused as Ybuf after GEMM1
  size_t hbytes = (size_t)nSlotsMax * F_ * 2;
  size_t wbytes = (size_t)E_ * F_ * D_ * 2;

  __hip_bfloat16* Abuf = (__hip_bfloat16*)(ws + o); o += abytes;
  __hip_bfloat16* Hbuf = (__hip_bfloat16*)(ws + o); o += hbytes;
  size_t o_nw = o;
  __hip_bfloat16* wfc16 = (__hip_bfloat16*)(ws + o_nw);
  __hip_bfloat16* wpj16 = (__hip_bfloat16*)(ws + o_nw + wbytes);

  bool twoPass = (ws_size >= o_nw);                 // ~171 MB
  bool wB16    = (ws_size >= o_nw + 2 * wbytes);    // ~305 MB

  init_kernel<<<(nSlotsMax + 255)/256, 256, 0, stream>>>(rowTok, rowW, counts, cursors, nSlotsMax);
  gate_kernel<<<(T + 3)/4, 256, 0, stream>>>(x, gw, tidx, tw, counts, T);
  scan_kernel<<<1, 64, 0, stream>>>(counts, aligned);
  scatter_kernel<<<(T + 255)/256, 256, 0, stream>>>(tidx, tw, aligned, cursors, rowTok, rowW, tokSlot, T);

  if (twoPass){
    gather_kernel<<<nSlotsMax, 256, 0, stream>>>(x, rowTok, Abuf);
    unsigned short* Ybuf = (unsigned short*)Abuf;   // Abuf dead after GEMM1
    if (wB16){
      int n4 = E_ * F_ * D_ / 4;
      cvtw_kernel<<<2048, 256, 0, stream>>>(wfc, wfc16, n4);
      cvtw_kernel<<<2048, 256, 0, stream>>>(wpj, wpj16, n4);
      gemm_kernel<true, true><<<dim3(F_/128, rowTilesMax), 256, 0, stream>>>(
          Abuf, (const void*)wfc16, bfc, aligned, (unsigned short*)Hbuf);
      gemm_kernel<true, false><<<dim3(D_/128, rowTilesMax), 256, 0, stream>>>(
          Hbuf, (const void*)wpj16, bpj, aligned, Ybuf);
    } else {
      gemm_kernel<false, true><<<dim3(F_/128, rowTilesMax), 256, 0, stream>>>(
          Abuf, (const void*)wfc, bfc, aligned, (unsigned short*)Hbuf);
      gemm_kernel<false, false><<<dim3(D_/128, rowTilesMax), 256, 0, stream>>>(
          Hbuf, (const void*)wpj, bpj, aligned, Ybuf);
    }
    combine_kernel<<<T, 256, 0, stream>>>(Ybuf, tidx, tw, tokSlot, bpj, out);
  } else {
    // emergency fallback: round-1 fused kernel
    hipMemsetAsync(d_out, 0, (size_t)out_size * 4, stream);
    int fusedTiles = nSlotsMax / 64;
    bool b16 = (ws_size >= o_rout + 2 * wbytes);
    __hip_bfloat16* fwfc16 = (__hip_bfloat16*)(ws + o_rout);
    __hip_bfloat16* fwpj16 = (__hip_bfloat16*)(ws + o_rout + wbytes);
    if (b16){
      int n4 = E_ * F_ * D_ / 4;
      cvtw_kernel<<<2048, 256, 0, stream>>>(wfc, fwfc16, n4);
      cvtw_kernel<<<2048, 256, 0, stream>>>(wpj, fwpj16, n4);
      hipFuncSetAttribute(reinterpret_cast<const void*>(&moe_tile_kernel<true>),
                          hipFuncAttributeMaxDynamicSharedMemorySize, SMEM_BYTES);
      moe_tile_kernel<true><<<fusedTiles, 512, SMEM_BYTES, stream>>>(
          x, (const void*)fwfc16, (const void*)fwpj16, bfc, bpj, rowTok, rowW, aligned, out);
    } else {
      hipFuncSetAttribute(reinterpret_cast<const void*>(&moe_tile_kernel<false>),
                          hipFuncAttributeMaxDynamicSharedMemorySize, SMEM_BYTES);
      moe_tile_kernel<false><<<fusedTiles, 512, SMEM_BYTES, stream>>>(
          x, (const void*)wfc, (const void*)wpj, bfc, bpj, rowTok, rowW, aligned, out);
    }
  }
}